// Round 5
// baseline (63.098 us; speedup 1.0000x reference)
//
#include <hip/hip_runtime.h>
#include <math.h>

// TrueRingDilatedAttention R5.
// Identity: gathered K/V = each of 1024 local keys exactly 4x
//   -> softmax over 1024 keys, denom = 4*S + EPS, out = 4*PV/denom.
// R5 vs R4: (1) 2-wave blocks (64 q/block) -> grid 1024 = 4 blocks/CU,
// 16 waves/CU; (2) double-buffered K LDS + V-reg prefetch: tile t+1 loads
// issued before tile t compute, drained by the compiler's vmcnt(0) at the
// single end-of-iteration barrier. Numerics identical to R4.

typedef __attribute__((ext_vector_type(8))) short bf16x8;
typedef __attribute__((ext_vector_type(4))) float f32x4;

constexpr int HEADS = 16;
constexpr int NQ    = 4096;
constexpr int NK    = 1024;
constexpr int KB    = 64;        // keys per tile
constexpr int NT    = NK / KB;   // 16 tiles
constexpr float EPS = 1e-8f;

// per-(h,kt) image layout in ws
constexpr int IMG_KH = 0;        // 8KB swizzled K-hi LDS image
constexpr int IMG_KL = 8192;     // 8KB swizzled K-lo LDS image
constexpr int IMG_VF = 16384;    // 8KB V fragment stream (PV B operand)
constexpr int IMG_SZ = 24576;

__device__ __forceinline__ ushort bf16_rn(float f) {
    uint u = __float_as_uint(f);
    u += 0x7FFF + ((u >> 16) & 1);
    return (ushort)(u >> 16);
}
__device__ __forceinline__ float bf16_f(ushort h) {
    return __uint_as_float(((uint)h) << 16);
}
// 128B rows, XOR swizzle at 16B granularity
__device__ __forceinline__ int swz(int row, int b) {
    return row * 128 + (b ^ ((row & 7) << 4));
}
__device__ __forceinline__ void load_lds16(const void* g, void* l) {
    __builtin_amdgcn_global_load_lds(
        (const __attribute__((address_space(1))) void*)g,
        (__attribute__((address_space(3))) void*)l, 16, 0, 0);
}

// ---------------- pre-pass: build per-(h,kt) images ----------------
__global__ __launch_bounds__(256)
void prepass(const float* __restrict__ kg, const float* __restrict__ vg,
             char* __restrict__ ws)
{
    const int kt = blockIdx.x;
    const int h  = blockIdx.y;
    const int kb = kt * KB;
    char* img = ws + (size_t)(h * NT + kt) * IMG_SZ;
    const int tid = threadIdx.x;

    // K hi/lo swizzled images: element (j,d) chunked as ushort4 (4 d's)
    const float4* k4 = reinterpret_cast<const float4*>(kg);
    #pragma unroll
    for (int i = 0; i < 4; ++i) {
        int fi = i * 256 + tid;
        int j = fi >> 4, dq = fi & 15;
        float4 kv = k4[(size_t)(kb + j) * 256 + h * 16 + dq];
        float kvals[4] = {kv.x, kv.y, kv.z, kv.w};
        ushort4 hi4, lo4;
        ushort* hp = (ushort*)&hi4; ushort* lp = (ushort*)&lo4;
        #pragma unroll
        for (int e = 0; e < 4; ++e) {
            ushort hh = bf16_rn(kvals[e]);
            hp[e] = hh;
            lp[e] = bf16_rn(kvals[e] - bf16_f(hh));
        }
        int addr = swz(j, dq * 8);
        *(ushort4*)(img + IMG_KH + addr) = hi4;
        *(ushort4*)(img + IMG_KL + addr) = lo4;
    }

    // V fragment stream: unit u = (frag f = cc*4+td) * 64 + lane
    #pragma unroll
    for (int i = 0; i < 2; ++i) {
        int u = i * 256 + tid;
        int f = u >> 6, l = u & 63;
        int cc = f >> 2, td = f & 3;
        int g = l >> 4, c = l & 15;
        ushort4 lo, hi;
        ushort* lp = (ushort*)&lo; ushort* hp = (ushort*)&hi;
        #pragma unroll
        for (int e = 0; e < 4; ++e) {
            lp[e] = bf16_rn(vg[(size_t)(kb + cc * 32 + g * 8 + e) * 1024 + h * 64 + td * 16 + c]);
            hp[e] = bf16_rn(vg[(size_t)(kb + cc * 32 + g * 8 + 4 + e) * 1024 + h * 64 + td * 16 + c]);
        }
        *(ushort4*)(img + IMG_VF + u * 16)     = lo;
        *(ushort4*)(img + IMG_VF + u * 16 + 8) = hi;
    }
}

// ---------------- main kernel: 2 waves/block, 64 q/block ----------------
__global__ __launch_bounds__(128, 2)
void ring_attn_mfma3(const float* __restrict__ qg,
                     const char* __restrict__ ws,
                     float* __restrict__ outg)
{
    __shared__ char   Klds[2][16384];  // dbuf: [Kh 8KB | Kl 8KB] swizzled
    __shared__ ushort Pl[2][32 * 64];  // per-wave P: 32 q x 64 k

    const int qblk = blockIdx.x;       // 64 q per block
    const int h    = blockIdx.y;
    const int tid  = threadIdx.x;
    const int w    = tid >> 6;
    const int lane = tid & 63;
    const int g    = lane >> 4;
    const int c    = lane & 15;

    const int qbase = qblk * 64 + w * 32;   // wave covers 32 q (halves A,B)

    // Q fragments, scale 1/8 folded. [half][cc]
    bf16x8 qh[2][2], ql[2][2];
    {
        const float4* q4 = reinterpret_cast<const float4*>(qg);
        #pragma unroll
        for (int H = 0; H < 2; ++H)
            #pragma unroll
            for (int cc = 0; cc < 2; ++cc) {
                int qi = qbase + H * 16 + c;
                int base = (qi * 1024 + h * 64 + cc * 32 + g * 8) >> 2;
                float4 a = q4[base], b = q4[base + 1];
                float vals[8] = {a.x, a.y, a.z, a.w, b.x, b.y, b.z, b.w};
                #pragma unroll
                for (int e = 0; e < 8; ++e) {
                    float x = vals[e] * 0.125f;
                    ushort hi = bf16_rn(x);
                    qh[H][cc][e] = (short)hi;
                    ql[H][cc][e] = (short)bf16_rn(x - bf16_f(hi));
                }
            }
    }

    f32x4 oA[4], oB[4];
    #pragma unroll
    for (int t = 0; t < 4; ++t)
        #pragma unroll
        for (int r = 0; r < 4; ++r) { oA[t][r] = 0.f; oB[t][r] = 0.f; }
    float mA = -INFINITY, mB = -INFINITY, lA = 0.f, lB = 0.f;

    const char* himg = ws + (size_t)h * NT * IMG_SZ;

    bf16x8 vb[2][4], vbn[2][4];

    // ---- prologue: stage tile 0 (K DMA + V regs)
    {
        const char* img0 = himg;
        #pragma unroll
        for (int i = 0; i < 8; ++i) {
            int off = w * 8192 + i * 1024;
            load_lds16(img0 + off + lane * 16, &Klds[0][off]);
        }
        #pragma unroll
        for (int f = 0; f < 8; ++f)
            vb[f >> 2][f & 3] = *(const bf16x8*)(img0 + IMG_VF + (f * 64 + lane) * 16);
    }
    __syncthreads();   // vmcnt(0): tile-0 K + V in place

    #pragma unroll 1
    for (int kt = 0; kt < NT; ++kt) {
        const int cur = kt & 1;
        const char* Kc = &Klds[cur][0];

        // ---- issue tile kt+1 loads (overlap with this tile's compute)
        if (kt + 1 < NT) {
            const char* img = himg + (size_t)(kt + 1) * IMG_SZ;
            #pragma unroll
            for (int i = 0; i < 8; ++i) {
                int off = w * 8192 + i * 1024;
                load_lds16(img + off + lane * 16, &Klds[cur ^ 1][off]);
            }
            #pragma unroll
            for (int f = 0; f < 8; ++f)
                vbn[f >> 2][f & 3] = *(const bf16x8*)(img + IMG_VF + (f * 64 + lane) * 16);
        }

        // ---- QK^T (swapped): S[key][q], 6 MFMA per (t,cc)
        f32x4 sA[4], sB[4];
        #pragma unroll
        for (int t = 0; t < 4; ++t)
            #pragma unroll
            for (int r = 0; r < 4; ++r) { sA[t][r] = 0.f; sB[t][r] = 0.f; }
        #pragma unroll
        for (int t = 0; t < 4; ++t) {
            #pragma unroll
            for (int cc = 0; cc < 2; ++cc) {
                int addr = swz(16 * t + c, 64 * cc + 16 * g);
                bf16x8 ah = *(const bf16x8*)(Kc + addr);
                bf16x8 al = *(const bf16x8*)(Kc + 8192 + addr);
                sA[t] = __builtin_amdgcn_mfma_f32_16x16x32_bf16(ah, qh[0][cc], sA[t], 0, 0, 0);
                sA[t] = __builtin_amdgcn_mfma_f32_16x16x32_bf16(al, qh[0][cc], sA[t], 0, 0, 0);
                sA[t] = __builtin_amdgcn_mfma_f32_16x16x32_bf16(ah, ql[0][cc], sA[t], 0, 0, 0);
                sB[t] = __builtin_amdgcn_mfma_f32_16x16x32_bf16(ah, qh[1][cc], sB[t], 0, 0, 0);
                sB[t] = __builtin_amdgcn_mfma_f32_16x16x32_bf16(al, qh[1][cc], sB[t], 0, 0, 0);
                sB[t] = __builtin_amdgcn_mfma_f32_16x16x32_bf16(ah, ql[1][cc], sB[t], 0, 0, 0);
            }
        }
        // lane (g,c): s*[t][r] = S[key=16t+4g+r][q = half_base + c]

        // ---- online softmax + P write, per half
        #pragma unroll
        for (int H = 0; H < 2; ++H) {
            f32x4* s = H ? sB : sA;
            float& m_run = H ? mB : mA;
            float& l_run = H ? lB : lA;
            f32x4* o = H ? oB : oA;

            float tm = -INFINITY;
            #pragma unroll
            for (int t = 0; t < 4; ++t)
                #pragma unroll
                for (int r = 0; r < 4; ++r) tm = fmaxf(tm, s[t][r]);
            tm = fmaxf(tm, __shfl_xor(tm, 16));
            tm = fmaxf(tm, __shfl_xor(tm, 32));
            float m_new = fmaxf(m_run, tm);
            float alpha = __expf(m_run - m_new);
            m_run = m_new;

            float psum = 0.f;
            #pragma unroll
            for (int t = 0; t < 4; ++t) {
                ushort4 pk;
                ushort* pp = (ushort*)&pk;
                #pragma unroll
                for (int r = 0; r < 4; ++r) {
                    float p = __expf(s[t][r] - m_new);
                    ushort pb = bf16_rn(p);
                    pp[r] = pb;
                    psum += bf16_f(pb);
                }
                *(ushort4*)((char*)(&Pl[w][0]) + swz(H * 16 + c, 32 * t + 8 * g)) = pk;
            }
            psum += __shfl_xor(psum, 16);
            psum += __shfl_xor(psum, 32);
            l_run = l_run * alpha + psum;

            float a0 = __shfl(alpha, 4 * g + 0);
            float a1 = __shfl(alpha, 4 * g + 1);
            float a2 = __shfl(alpha, 4 * g + 2);
            float a3 = __shfl(alpha, 4 * g + 3);
            #pragma unroll
            for (int td = 0; td < 4; ++td) {
                o[td][0] *= a0; o[td][1] *= a1;
                o[td][2] *= a2; o[td][3] *= a3;
            }
        }

        // ---- PV: A = P (wave-private LDS), B = vb regs (current tile)
        #pragma unroll
        for (int cc = 0; cc < 2; ++cc) {
            bf16x8 paA = *(const bf16x8*)((char*)(&Pl[w][0]) + swz(c,      64 * cc + 16 * g));
            bf16x8 paB = *(const bf16x8*)((char*)(&Pl[w][0]) + swz(16 + c, 64 * cc + 16 * g));
            #pragma unroll
            for (int td = 0; td < 4; ++td) {
                oA[td] = __builtin_amdgcn_mfma_f32_16x16x32_bf16(paA, vb[cc][td], oA[td], 0, 0, 0);
                oB[td] = __builtin_amdgcn_mfma_f32_16x16x32_bf16(paB, vb[cc][td], oB[td], 0, 0, 0);
            }
        }

        // rotate V prefetch
        if (kt + 1 < NT) {
            #pragma unroll
            for (int cc = 0; cc < 2; ++cc)
                #pragma unroll
                for (int td = 0; td < 4; ++td) vb[cc][td] = vbn[cc][td];
        }

        // single barrier per tile: compiler emits s_waitcnt vmcnt(0) lgkmcnt(0)
        // here -> next tile's K DMA + V regs complete, this tile's reads done.
        __syncthreads();
    }

    // ---- epilogue: rows q' = H*16 + 4g+r, cols d = 16td + c
    #pragma unroll
    for (int H = 0; H < 2; ++H) {
        f32x4* o = H ? oB : oA;
        float lr = H ? lB : lA;
        #pragma unroll
        for (int r = 0; r < 4; ++r) {
            float lq  = __shfl(lr, 4 * g + r);
            float inv = 4.f / (4.f * lq + EPS);
            int qrow  = qbase + H * 16 + 4 * g + r;
            #pragma unroll
            for (int td = 0; td < 4; ++td)
                outg[(size_t)qrow * 1024 + h * 64 + 16 * td + c] = o[td][r] * inv;
        }
    }
}

extern "C" void kernel_launch(void* const* d_in, const int* in_sizes, int n_in,
                              void* d_out, int out_size, void* d_ws, size_t ws_size,
                              hipStream_t stream) {
    const float* q = (const float*)d_in[0];
    const float* k = (const float*)d_in[1];
    const float* v = (const float*)d_in[2];
    float* out = (float*)d_out;
    char* ws = (char*)d_ws;   // 16*16*24576 = 6 MB

    prepass<<<dim3(NT, HEADS), dim3(256), 0, stream>>>(k, v, ws);
    ring_attn_mfma3<<<dim3(NQ / 64, HEADS), dim3(128), 0, stream>>>(q, ws, out);
}

// Round 6
// 47.536 us; speedup vs baseline: 1.3274x; 1.3274x over previous
//
#include <hip/hip_runtime.h>
#include <math.h>

// TrueRingDilatedAttention R6.
// Identity: gathered K/V (4096) = each of 1024 local keys exactly 4x
//   -> softmax over 1024 keys, denom = 4*S + EPS, out = 4*PV/denom.
// R6: pure-fp16 operands (error budget ~1e-3 << 1.06e-2 threshold);
// prepass emits K AND V as per-lane MFMA fragment streams; main kernel has
// ZERO barriers (K,V stream straight to registers, 2-tile-deep named double
// buffers; only wave-private P touches LDS). Counted vmcnt waits survive
// because nothing forces vmcnt(0).

typedef __attribute__((ext_vector_type(8))) _Float16 f16x8;   // 4 VGPRs
typedef __attribute__((ext_vector_type(4))) float    f32x4;

constexpr int HEADS = 16;
constexpr int NQ    = 4096;
constexpr int NK    = 1024;
constexpr int KB    = 64;        // keys per tile
constexpr int NT    = NK / KB;   // 16 tiles
constexpr float EPS = 1e-8f;

constexpr int IMG_K  = 0;        // 8KB K fragment stream (QK^T A operand)
constexpr int IMG_V  = 8192;     // 8KB V fragment stream (PV   B operand)
constexpr int IMG_SZ = 16384;

// 128B rows, XOR swizzle at 16B granularity (wave-private P buffer)
__device__ __forceinline__ int swz(int row, int b) {
    return row * 128 + (b ^ ((row & 7) << 4));
}

// ---------------- pre-pass: build per-(h,kt) fragment streams ----------------
__global__ __launch_bounds__(256)
void prepass(const float* __restrict__ kg, const float* __restrict__ vg,
             char* __restrict__ ws)
{
    const int kt = blockIdx.x;
    const int h  = blockIdx.y;
    const int kb = kt * KB;
    char* img = ws + (size_t)(h * NT + kt) * IMG_SZ;
    const int tid = threadIdx.x;

    // K frags: unit u = f*64 + lane, f = t*2+cc.
    // lane (g,c) of frag (t,cc): K[kb+16t+c][32cc+8g+e], e=0..7, scaled 1/8.
    #pragma unroll
    for (int i = 0; i < 2; ++i) {
        int u = i * 256 + tid;
        int f = u >> 6, l = u & 63;
        int t = f >> 1, cc = f & 1;
        int g = l >> 4, c = l & 15;
        const float* src = kg + (size_t)(kb + 16 * t + c) * 1024 + h * 64 + 32 * cc + 8 * g;
        float4 a = *(const float4*)src;
        float4 b = *(const float4*)(src + 4);
        f16x8 kk;
        kk[0] = (_Float16)(a.x * 0.125f); kk[1] = (_Float16)(a.y * 0.125f);
        kk[2] = (_Float16)(a.z * 0.125f); kk[3] = (_Float16)(a.w * 0.125f);
        kk[4] = (_Float16)(b.x * 0.125f); kk[5] = (_Float16)(b.y * 0.125f);
        kk[6] = (_Float16)(b.z * 0.125f); kk[7] = (_Float16)(b.w * 0.125f);
        *(f16x8*)(img + IMG_K + u * 16) = kk;
    }

    // V frags: unit u = f*64 + lane, f = cc*4+td.
    // lane (g,c) of frag (cc,td): V[kb+cc*32+g*8+e][h*64+td*16+c]
    #pragma unroll
    for (int i = 0; i < 2; ++i) {
        int u = i * 256 + tid;
        int f = u >> 6, l = u & 63;
        int cc = f >> 2, td = f & 3;
        int g = l >> 4, c = l & 15;
        f16x8 vv;
        #pragma unroll
        for (int e = 0; e < 8; ++e)
            vv[e] = (_Float16)vg[(size_t)(kb + cc * 32 + g * 8 + e) * 1024 + h * 64 + td * 16 + c];
        *(f16x8*)(img + IMG_V + u * 16) = vv;
    }
}

// ---------------- main kernel: 1 wave/block, no barriers ----------------
__global__ __launch_bounds__(64, 2)
void ring_attn_f16(const float* __restrict__ qg,
                   const char* __restrict__ ws,
                   float* __restrict__ outg)
{
    __shared__ char Pl[4096];          // wave-private P: 32 q x 64 k fp16

    const int qw   = blockIdx.x;       // 32 q per wave
    const int h    = blockIdx.y;
    const int lane = threadIdx.x;
    const int g    = lane >> 4;
    const int c    = lane & 15;
    const int qbase = qw * 32;

    // ---- Q fragments fp16 (scale already folded into K)
    f16x8 qf[2][2];
    #pragma unroll
    for (int H = 0; H < 2; ++H)
        #pragma unroll
        for (int cc = 0; cc < 2; ++cc) {
            const float* src = qg + (size_t)(qbase + 16 * H + c) * 1024 + h * 64 + 32 * cc + 8 * g;
            float4 a = *(const float4*)src;
            float4 b = *(const float4*)(src + 4);
            f16x8 qq;
            qq[0] = (_Float16)a.x; qq[1] = (_Float16)a.y;
            qq[2] = (_Float16)a.z; qq[3] = (_Float16)a.w;
            qq[4] = (_Float16)b.x; qq[5] = (_Float16)b.y;
            qq[6] = (_Float16)b.z; qq[7] = (_Float16)b.w;
            qf[H][cc] = qq;
        }

    f32x4 oA[4], oB[4];
    #pragma unroll
    for (int t = 0; t < 4; ++t)
        #pragma unroll
        for (int r = 0; r < 4; ++r) { oA[t][r] = 0.f; oB[t][r] = 0.f; }
    float mA = -INFINITY, mB = -INFINITY, lA = 0.f, lB = 0.f;

    const char* himg = ws + (size_t)h * NT * IMG_SZ + lane * 16;

    f16x8 k0[8], v0[8], k1[8], v1[8];

    // ---- prologue: 2-deep prefetch (tiles 0 and 1)
    #pragma unroll
    for (int f = 0; f < 8; ++f) {
        k0[f] = *(const f16x8*)(himg + IMG_K + f * 1024);
        v0[f] = *(const f16x8*)(himg + IMG_V + f * 1024);
    }
    #pragma unroll
    for (int f = 0; f < 8; ++f) {
        k1[f] = *(const f16x8*)(himg + IMG_SZ + IMG_K + f * 1024);
        v1[f] = *(const f16x8*)(himg + IMG_SZ + IMG_V + f * 1024);
    }

    // one full tile: QK^T -> online softmax -> P (wave-private LDS) -> PV
    auto tile = [&](const f16x8 (&kf)[8], const f16x8 (&vf)[8]) {
        f32x4 s0[4], s1[4];
        #pragma unroll
        for (int t = 0; t < 4; ++t)
            #pragma unroll
            for (int r = 0; r < 4; ++r) { s0[t][r] = 0.f; s1[t][r] = 0.f; }
        #pragma unroll
        for (int t = 0; t < 4; ++t)
            #pragma unroll
            for (int cc = 0; cc < 2; ++cc) {
                s0[t] = __builtin_amdgcn_mfma_f32_16x16x32_f16(kf[2 * t + cc], qf[0][cc], s0[t], 0, 0, 0);
                s1[t] = __builtin_amdgcn_mfma_f32_16x16x32_f16(kf[2 * t + cc], qf[1][cc], s1[t], 0, 0, 0);
            }
        // lane (g,c): sH[t][r] = S[key=16t+4g+r][q = 16H + c]

        #pragma unroll
        for (int H = 0; H < 2; ++H) {
            f32x4* s = H ? s1 : s0;
            float& m_run = H ? mB : mA;
            float& l_run = H ? lB : lA;
            f32x4* o = H ? oB : oA;

            float tm = -INFINITY;
            #pragma unroll
            for (int t = 0; t < 4; ++t)
                #pragma unroll
                for (int r = 0; r < 4; ++r) tm = fmaxf(tm, s[t][r]);
            tm = fmaxf(tm, __shfl_xor(tm, 16));
            tm = fmaxf(tm, __shfl_xor(tm, 32));
            float m_new = fmaxf(m_run, tm);
            float alpha = __expf(m_run - m_new);
            m_run = m_new;

            float psum = 0.f;
            #pragma unroll
            for (int t = 0; t < 4; ++t) {
                union { ushort4 u4; _Float16 hh[4]; } pk;
                #pragma unroll
                for (int r = 0; r < 4; ++r) {
                    float p = __expf(s[t][r] - m_new);
                    psum += p;
                    pk.hh[r] = (_Float16)p;
                }
                *(ushort4*)(Pl + swz(H * 16 + c, 32 * t + 8 * g)) = pk.u4;
            }
            psum += __shfl_xor(psum, 16);
            psum += __shfl_xor(psum, 32);
            l_run = l_run * alpha + psum;

            float a0 = __shfl(alpha, 4 * g + 0);
            float a1 = __shfl(alpha, 4 * g + 1);
            float a2 = __shfl(alpha, 4 * g + 2);
            float a3 = __shfl(alpha, 4 * g + 3);
            #pragma unroll
            for (int td = 0; td < 4; ++td) {
                o[td][0] *= a0; o[td][1] *= a1;
                o[td][2] *= a2; o[td][3] *= a3;
            }
        }

        // PV: A = P (wave-private LDS), B = vf regs
        #pragma unroll
        for (int cc = 0; cc < 2; ++cc) {
            f16x8 pa0 = *(const f16x8*)(Pl + swz(c,      64 * cc + 16 * g));
            f16x8 pa1 = *(const f16x8*)(Pl + swz(16 + c, 64 * cc + 16 * g));
            #pragma unroll
            for (int td = 0; td < 4; ++td) {
                oA[td] = __builtin_amdgcn_mfma_f32_16x16x32_f16(pa0, vf[cc * 4 + td], oA[td], 0, 0, 0);
                oB[td] = __builtin_amdgcn_mfma_f32_16x16x32_f16(pa1, vf[cc * 4 + td], oB[td], 0, 0, 0);
            }
        }
    };

    #pragma unroll 1
    for (int kt = 0; kt < NT; kt += 2) {
        tile(k0, v0);
        if (kt + 2 < NT) {
            const char* img = himg + (size_t)(kt + 2) * IMG_SZ;
            #pragma unroll
            for (int f = 0; f < 8; ++f) {
                k0[f] = *(const f16x8*)(img + IMG_K + f * 1024);
                v0[f] = *(const f16x8*)(img + IMG_V + f * 1024);
            }
        }
        tile(k1, v1);
        if (kt + 3 < NT) {
            const char* img = himg + (size_t)(kt + 3) * IMG_SZ;
            #pragma unroll
            for (int f = 0; f < 8; ++f) {
                k1[f] = *(const f16x8*)(img + IMG_K + f * 1024);
                v1[f] = *(const f16x8*)(img + IMG_V + f * 1024);
            }
        }
    }

    // ---- epilogue: rows q' = H*16 + 4g+r, cols d = 16td + c
    #pragma unroll
    for (int H = 0; H < 2; ++H) {
        f32x4* o = H ? oB : oA;
        float lr = H ? lB : lA;
        #pragma unroll
        for (int r = 0; r < 4; ++r) {
            float lq  = __shfl(lr, 4 * g + r);
            float inv = 4.f / (4.f * lq + EPS);
            int qrow  = qbase + H * 16 + 4 * g + r;
            #pragma unroll
            for (int td = 0; td < 4; ++td)
                outg[(size_t)qrow * 1024 + h * 64 + 16 * td + c] = o[td][r] * inv;
        }
    }
}

extern "C" void kernel_launch(void* const* d_in, const int* in_sizes, int n_in,
                              void* d_out, int out_size, void* d_ws, size_t ws_size,
                              hipStream_t stream) {
    const float* q = (const float*)d_in[0];
    const float* k = (const float*)d_in[1];
    const float* v = (const float*)d_in[2];
    float* out = (float*)d_out;
    char* ws = (char*)d_ws;   // 16*16*16384 = 4 MB

    prepass<<<dim3(NT, HEADS), dim3(256), 0, stream>>>(k, v, ws);
    ring_attn_f16<<<dim3(NQ / 32, HEADS), dim3(64), 0, stream>>>(q, ws, out);
}